// Round 5
// baseline (335.501 us; speedup 1.0000x reference)
//
#include <hip/hip_runtime.h>

#define HH 16
#define SS 4096
#define DHD 128
#define BR 128        // q rows per block (32 per wave, nt=2)
#define BC 64         // k rows per tile
#define LDK 144       // bf16/row k_s: 288B
#define LDQS 136      // bf16/row Q staging temp (borrowed region)
#define LDV 72        // bf16/row vt_s: 144B -> single b128 V-frag reads
#define LDPT 72       // bf16/row pT_s
#define LDOS 132      // f32/row epilogue overlay: 528B
#define DM (HH * DHD)

typedef __bf16 bf16x8_t __attribute__((ext_vector_type(8)));
typedef __bf16 bf16x4_t __attribute__((ext_vector_type(4)));
typedef float  f32x4_t  __attribute__((ext_vector_type(4)));

// LDS-only barrier: leaves the global prefetch (registers) in flight.
#define BAR() asm volatile("s_waitcnt lgkmcnt(0)\n\ts_barrier" ::: "memory")

__device__ __forceinline__ f32x4_t vmax4(f32x4_t a, f32x4_t b) {
    f32x4_t r;
    r[0] = fmaxf(a[0], b[0]); r[1] = fmaxf(a[1], b[1]);
    r[2] = fmaxf(a[2], b[2]); r[3] = fmaxf(a[3], b[3]);
    return r;
}

__global__ __launch_bounds__(256, 2)
void fa_fwd(const float* __restrict__ q, const float* __restrict__ k,
            const float* __restrict__ v, float* __restrict__ out)
{
    // Pair (b, b+256) -> qt + qt' = 31: co-resident blocks on one CU sum to a
    // constant 66 k-iters (dispatch round-robin heuristic; perf-only).
    const int b  = blockIdx.x;
    const int h  = b & 15;
    const int qt = (b < 256) ? (b >> 4) : (47 - (b >> 4));
    const int jend = 2 * qt + 2;

    const int tid  = threadIdx.x;
    const int wave = tid >> 6;
    const int lane = tid & 63;
    const int l16  = lane & 15;
    const int quad = lane >> 4;
    const int rK   = tid >> 5;               // staging row base (0..7)
    const int c4   = tid & 31;               // staging float4 col
    const int dbase = (wave & 1) * 64;       // V-transpose staging split
    const int rbase = (wave >> 1) * 32;

    // [k_s 18432][vt_s 18432][pT_s 18432] = 55296 B; Q staging + epilogue
    // overlay borrow the front region.
    __shared__ __align__(16) char smem[55296];
    unsigned short* k_s  = (unsigned short*)smem;
    unsigned short* vt_s = (unsigned short*)(smem + 18432);
    unsigned short* pT_s = (unsigned short*)(smem + 36864);
    unsigned short* qtmp = (unsigned short*)smem;   // 128*136*2 = 34816 B
    float* os = (float*)smem;                       // 64*132*4 = 33792 B

    const size_t hoff = (size_t)h * SS * DHD;
    const float* qh = q + hoff;
    const float* kh = k + hoff;
    const float* vh = v + hoff;

    float4 kreg[8];
    float  vreg[8][4];
    auto issue = [&](int j) {
        const float* kb = kh + (size_t)j * BC * DHD;
        #pragma unroll
        for (int i = 0; i < 8; ++i)
            kreg[i] = ((const float4*)(kb + (size_t)(rK + i * 8) * DHD))[c4];
        const float* vb = vh + (size_t)j * BC * DHD + dbase + lane;
        #pragma unroll
        for (int p = 0; p < 8; ++p) {
            const float* vp = vb + (size_t)(rbase + p * 4) * DHD;
            vreg[p][0] = vp[0];
            vreg[p][1] = vp[DHD];
            vreg[p][2] = vp[2 * DHD];
            vreg[p][3] = vp[3 * DHD];
        }
    };

    // 1/sqrt(128) * log2(e): softmax done in exp2 domain.
    const float scale = 0.088388347648318447f * 1.4426950408889634f;
    issue(0);

    // ---- stage Q (scale folded) into borrowed region ----
    #pragma unroll
    for (int i = 0; i < 16; ++i) {
        int idx = tid + i * 256;           // 0..4095
        int r   = idx >> 5;
        int cc  = idx & 31;
        float4 val = ((const float4*)(qh + (size_t)(qt * BR + r) * DHD))[cc];
        bf16x4_t bb;
        bb[0] = (__bf16)(val.x * scale); bb[1] = (__bf16)(val.y * scale);
        bb[2] = (__bf16)(val.z * scale); bb[3] = (__bf16)(val.w * scale);
        *(bf16x4_t*)&qtmp[r * LDQS + cc * 4] = bb;
    }
    __syncthreads();

    // ---- Q B-fragments: wave owns q rows wave*32 .. +32 (nt=2) ----
    bf16x8_t qf[2][4];
    #pragma unroll
    for (int nt = 0; nt < 2; ++nt)
        #pragma unroll
        for (int kc = 0; kc < 4; ++kc)
            qf[nt][kc] = *(const bf16x8_t*)
                &qtmp[(wave * 32 + nt * 16 + l16) * LDQS + kc * 32 + quad * 8];

    f32x4_t oacc[8][2];                // O^T: mt=d-tile, nt=q-tile, col q=l16
    #pragma unroll
    for (int mt = 0; mt < 8; ++mt)
        #pragma unroll
        for (int nt = 0; nt < 2; ++nt) oacc[mt][nt] = (f32x4_t)(0.0f);
    float mi[2] = { -INFINITY, -INFINITY }, li[2] = { 0.0f, 0.0f };

    for (int j = 0; j < jend; ++j) {
        BAR();                         // own qf/frag lgkm drained; vm in flight
        // ---- commit prefetched K / V^T ----
        #pragma unroll
        for (int i = 0; i < 8; ++i) {
            bf16x4_t bb;
            bb[0] = (__bf16)kreg[i].x; bb[1] = (__bf16)kreg[i].y;
            bb[2] = (__bf16)kreg[i].z; bb[3] = (__bf16)kreg[i].w;
            *(bf16x4_t*)&k_s[(rK + i * 8) * LDK + c4 * 4] = bb;
        }
        #pragma unroll
        for (int p = 0; p < 8; ++p) {
            bf16x4_t bb;
            bb[0] = (__bf16)vreg[p][0]; bb[1] = (__bf16)vreg[p][1];
            bb[2] = (__bf16)vreg[p][2]; bb[3] = (__bf16)vreg[p][3];
            *(bf16x4_t*)&vt_s[(dbase + lane) * LDV + rbase + p * 4] = bb;
        }
        if (j + 1 < jend) issue(j + 1);
        BAR();

        // ---- S^T = K Q^T : 4 m-tiles (k) x 2 n-tiles (q) ----
        f32x4_t sa[4][2];
        #pragma unroll
        for (int mt = 0; mt < 4; ++mt)
            #pragma unroll
            for (int nt = 0; nt < 2; ++nt) sa[mt][nt] = (f32x4_t)(0.0f);
        #pragma unroll
        for (int kc = 0; kc < 4; ++kc)
            #pragma unroll
            for (int mt = 0; mt < 4; ++mt) {
                bf16x8_t kf = *(const bf16x8_t*)
                    &k_s[(mt * 16 + l16) * LDK + kc * 32 + quad * 8];
                sa[mt][0] = __builtin_amdgcn_mfma_f32_16x16x32_bf16(kf, qf[0][kc], sa[mt][0], 0, 0, 0);
                sa[mt][1] = __builtin_amdgcn_mfma_f32_16x16x32_bf16(kf, qf[1][kc], sa[mt][1], 0, 0, 0);
            }

        // ---- causal mask (last two tiles): row k, col q ----
        if (j >= 2 * qt) {
            const int cb = (j - 2 * qt) * 64;
            #pragma unroll
            for (int nt = 0; nt < 2; ++nt) {
                const int ql = wave * 32 + nt * 16 + l16;
                #pragma unroll
                for (int mt = 0; mt < 4; ++mt)
                    #pragma unroll
                    for (int r = 0; r < 4; ++r)
                        if (cb + mt * 16 + quad * 4 + r > ql)
                            sa[mt][nt][r] = -INFINITY;
            }
        }

        // ---- online softmax (exp2 domain), per nt; in-lane 16 + 2 shfls ----
        float a[2];
        bf16x4_t pkv[2][4];
        #pragma unroll
        for (int nt = 0; nt < 2; ++nt) {
            f32x4_t mv = vmax4(vmax4(sa[0][nt], sa[1][nt]),
                               vmax4(sa[2][nt], sa[3][nt]));
            float mx = fmaxf(fmaxf(mv[0], mv[1]), fmaxf(mv[2], mv[3]));
            mx = fmaxf(mx, __shfl_xor(mx, 16));
            mx = fmaxf(mx, __shfl_xor(mx, 32));
            float mnew = fmaxf(mi[nt], mx);
            a[nt] = exp2f(mi[nt] - mnew);
            mi[nt] = mnew;
            #pragma unroll
            for (int mt = 0; mt < 4; ++mt) {
                #pragma unroll
                for (int r = 0; r < 4; ++r) sa[mt][nt][r] = exp2f(sa[mt][nt][r] - mnew);
                pkv[nt][mt][0] = (__bf16)sa[mt][nt][0];
                pkv[nt][mt][1] = (__bf16)sa[mt][nt][1];
                pkv[nt][mt][2] = (__bf16)sa[mt][nt][2];
                pkv[nt][mt][3] = (__bf16)sa[mt][nt][3];
            }
            f32x4_t sv = (sa[0][nt] + sa[1][nt]) + (sa[2][nt] + sa[3][nt]);
            float rs = (sv[0] + sv[1]) + (sv[2] + sv[3]);
            rs += __shfl_xor(rs, 16);
            rs += __shfl_xor(rs, 32);
            li[nt] = li[nt] * a[nt] + rs;
        }

        // ---- P^T -> LDS (wave-local rows; same-wave order => no barrier) ----
        #pragma unroll
        for (int nt = 0; nt < 2; ++nt)
            #pragma unroll
            for (int mt = 0; mt < 4; ++mt)
                *(bf16x4_t*)&pT_s[(wave * 32 + nt * 16 + l16) * LDPT + mt * 16 + quad * 4] =
                    pkv[nt][mt];

        // ---- rescale O^T ----
        #pragma unroll
        for (int mt = 0; mt < 8; ++mt)
            #pragma unroll
            for (int nt = 0; nt < 2; ++nt) {
                oacc[mt][nt][0] *= a[nt]; oacc[mt][nt][1] *= a[nt];
                oacc[mt][nt][2] *= a[nt]; oacc[mt][nt][3] *= a[nt];
            }

        // ---- O^T += V^T P^T : 8 m-tiles (d) x 2 n-tiles (q) ----
        #pragma unroll
        for (int kc = 0; kc < 2; ++kc) {
            bf16x8_t pb0 = *(const bf16x8_t*)
                &pT_s[(wave * 32 + l16) * LDPT + kc * 32 + quad * 8];
            bf16x8_t pb1 = *(const bf16x8_t*)
                &pT_s[(wave * 32 + 16 + l16) * LDPT + kc * 32 + quad * 8];
            #pragma unroll
            for (int mt = 0; mt < 8; ++mt) {
                bf16x8_t vf = *(const bf16x8_t*)
                    &vt_s[(mt * 16 + l16) * LDV + kc * 32 + quad * 8];
                oacc[mt][0] = __builtin_amdgcn_mfma_f32_16x16x32_bf16(vf, pb0, oacc[mt][0], 0, 0, 0);
                oacc[mt][1] = __builtin_amdgcn_mfma_f32_16x16x32_bf16(vf, pb1, oacc[mt][1], 0, 0, 0);
            }
        }
    }

    // ---- epilogue: O^T -> overlay transpose -> coalesced fp32 stores ----
    float inv[2] = { 1.0f / li[0], 1.0f / li[1] };
    __syncthreads();                   // final-iter LDS frag reads drained
    #pragma unroll
    for (int p = 0; p < 2; ++p) {
        if ((wave >> 1) == p) {
            #pragma unroll
            for (int nt = 0; nt < 2; ++nt) {
                int q64 = (wave & 1) * 32 + nt * 16 + l16;
                #pragma unroll
                for (int mt = 0; mt < 8; ++mt) {
                    f32x4_t vv = oacc[mt][nt];
                    vv[0] *= inv[nt]; vv[1] *= inv[nt];
                    vv[2] *= inv[nt]; vv[3] *= inv[nt];
                    *(f32x4_t*)&os[q64 * LDOS + mt * 16 + quad * 4] = vv;
                }
            }
        }
        __syncthreads();
        #pragma unroll
        for (int i = 0; i < 8; ++i) {
            int r = rK + i * 8;        // 0..63
            float4 f4 = *(const float4*)&os[r * LDOS + c4 * 4];
            *(float4*)&out[(size_t)(qt * BR + p * 64 + r) * DM + h * DHD + c4 * 4] = f4;
        }
        if (p == 0) __syncthreads();
    }
}

extern "C" void kernel_launch(void* const* d_in, const int* in_sizes, int n_in,
                              void* d_out, int out_size, void* d_ws, size_t ws_size,
                              hipStream_t stream) {
    const float* q = (const float*)d_in[0];
    const float* k = (const float*)d_in[1];
    const float* v = (const float*)d_in[2];
    float* out = (float*)d_out;
    fa_fwd<<<dim3((SS / BR) * HH), dim3(256), 0, stream>>>(q, k, v, out);
}

// Round 7
// 312.228 us; speedup vs baseline: 1.0745x; 1.0745x over previous
//
#include <hip/hip_runtime.h>

#define HH 16
#define SS 4096
#define DHD 128
#define BC 64         // k rows per tile; q-tile = 64 rows (32 per consumer wave)
#define LDK 136       // bf16/row k bufs: 272B (16B-aligned, ~2-way banks on b128)
#define LDV 72        // bf16/row vt bufs: 144B (16B-aligned, ~2-way)
#define LDPT 72       // bf16/row pT
#define DM (HH * DHD)

// LDS byte offsets (no pointer arrays -> no addrspacecast initializers)
#define OFF_K0   0
#define OFF_K1   17408
#define OFF_VT0  34816
#define OFF_VT1  53248
#define OFF_PT   71680
#define SMEM_SZ  80896

typedef __bf16 bf16x8_t __attribute__((ext_vector_type(8)));
typedef __bf16 bf16x4_t __attribute__((ext_vector_type(4)));
typedef float  f32x4_t  __attribute__((ext_vector_type(4)));

// LDS-only barrier: producers' in-flight global loads survive it.
#define BAR() asm volatile("s_waitcnt lgkmcnt(0)\n\ts_barrier" ::: "memory")

__device__ __forceinline__ f32x4_t vmax4(f32x4_t a, f32x4_t b) {
    f32x4_t r;
    r[0] = fmaxf(a[0], b[0]); r[1] = fmaxf(a[1], b[1]);
    r[2] = fmaxf(a[2], b[2]); r[3] = fmaxf(a[3], b[3]);
    return r;
}

__global__ __launch_bounds__(256, 2)
void fa_fwd(const float* __restrict__ q, const float* __restrict__ k,
            const float* __restrict__ v, float* __restrict__ out)
{
    // 512 EQUAL blocks: q-tiles {g, 63-g} done sequentially inside one block
    // (65 k-iters each) -> duration-matched co-residency, 2 blocks/CU.
    const int b   = blockIdx.x;
    const int h   = b & 15;
    const int g   = b >> 4;            // 0..31
    const int qt0 = g, qt1 = 63 - g;
    const int n0  = g + 1;             // iters in tile 0
    const int J   = 65;                // total iters

    const int tid  = threadIdx.x;
    const int wave = tid >> 6;
    const int lane = tid & 63;
    const int l16  = lane & 15;
    const int quad = lane >> 4;

    __shared__ __align__(16) char smem[SMEM_SZ];
    unsigned short* pT_s = (unsigned short*)(smem + OFF_PT);

    const size_t hoff = (size_t)h * SS * DHD;
    const float* qh = q + hoff;
    const float* kh = k + hoff;
    const float* vh = v + hoff;

    // 1/sqrt(128) * log2(e): softmax in exp2 domain.
    const float scale = 0.088388347648318447f * 1.4426950408889634f;

    if (wave >= 2) {
        // ================= PRODUCER (waves 2,3) =================
        const int pl  = tid - 128;         // 0..127
        const int rK2 = pl >> 4;           // 0..7  (K row base)
        const int c16 = pl & 15;           // K float4 col
        float4 kreg[16];
        float  vreg[64];

        auto jof = [&](int ii) { return ii < n0 ? ii : ii - n0; };
        auto issue = [&](int j) {
            const float* kbp = kh + (size_t)j * BC * DHD;
            #pragma unroll
            for (int i = 0; i < 8; ++i) {
                const float4* rp = (const float4*)(kbp + (size_t)(rK2 + 8 * i) * DHD);
                kreg[2 * i]     = rp[c16];
                kreg[2 * i + 1] = rp[c16 + 16];
            }
            const float* vbp = vh + (size_t)j * BC * DHD + pl;
            #pragma unroll
            for (int s = 0; s < 64; ++s)
                vreg[s] = vbp[(size_t)s * DHD];
        };
        auto commit = [&](int buf) {
            unsigned short* kd = (unsigned short*)(smem + (buf ? OFF_K1 : OFF_K0));
            unsigned short* vd = (unsigned short*)(smem + (buf ? OFF_VT1 : OFF_VT0));
            #pragma unroll
            for (int i = 0; i < 8; ++i) {
                bf16x4_t b0, b1;
                b0[0] = (__bf16)kreg[2*i].x;   b0[1] = (__bf16)kreg[2*i].y;
                b0[2] = (__bf16)kreg[2*i].z;   b0[3] = (__bf16)kreg[2*i].w;
                b1[0] = (__bf16)kreg[2*i+1].x; b1[1] = (__bf16)kreg[2*i+1].y;
                b1[2] = (__bf16)kreg[2*i+1].z; b1[3] = (__bf16)kreg[2*i+1].w;
                *(bf16x4_t*)&kd[(rK2 + 8 * i) * LDK + c16 * 4]      = b0;
                *(bf16x4_t*)&kd[(rK2 + 8 * i) * LDK + c16 * 4 + 64] = b1;
            }
            #pragma unroll
            for (int s0 = 0; s0 < 16; ++s0) {
                bf16x4_t bb;
                bb[0] = (__bf16)vreg[4*s0];     bb[1] = (__bf16)vreg[4*s0+1];
                bb[2] = (__bf16)vreg[4*s0+2];   bb[3] = (__bf16)vreg[4*s0+3];
                *(bf16x4_t*)&vd[pl * LDV + s0 * 4] = bb;
            }
        };

        issue(jof(0));
        commit(0);
        issue(jof(1));
        BAR();
        for (int i = 0; i < J; ++i) {
            if (i + 1 < J) commit((i + 1) & 1);
            if (i + 2 < J) issue(jof(i + 2));
            BAR();
        }
        return;
    }

    // ================= CONSUMER (waves 0,1): 32 q-rows each =================
    bf16x8_t qf[2][4];
    auto loadQ = [&](int qt) {
        const float* qb = qh + (size_t)(qt * 64 + wave * 32) * DHD;
        #pragma unroll
        for (int nt = 0; nt < 2; ++nt)
            #pragma unroll
            for (int kc = 0; kc < 4; ++kc) {
                const float* row = qb + (size_t)(nt * 16 + l16) * DHD + kc * 32 + quad * 8;
                float4 a0 = *(const float4*)row;
                float4 a1 = *(const float4*)(row + 4);
                bf16x8_t f;
                f[0] = (__bf16)(a0.x * scale); f[1] = (__bf16)(a0.y * scale);
                f[2] = (__bf16)(a0.z * scale); f[3] = (__bf16)(a0.w * scale);
                f[4] = (__bf16)(a1.x * scale); f[5] = (__bf16)(a1.y * scale);
                f[6] = (__bf16)(a1.z * scale); f[7] = (__bf16)(a1.w * scale);
                qf[nt][kc] = f;
            }
    };

    f32x4_t oacc[8][2];
    float mi[2], li[2];
    auto resetAcc = [&]() {
        #pragma unroll
        for (int mt = 0; mt < 8; ++mt)
            #pragma unroll
            for (int nt = 0; nt < 2; ++nt) oacc[mt][nt] = (f32x4_t)(0.0f);
        mi[0] = mi[1] = -INFINITY;
        li[0] = li[1] = 0.0f;
    };
    auto storeTile = [&](int qt) {
        #pragma unroll
        for (int nt = 0; nt < 2; ++nt) {
            float iv = 1.0f / li[nt];
            float* op = out + (size_t)(qt * 64 + wave * 32 + nt * 16 + l16) * DM + h * DHD;
            #pragma unroll
            for (int mt = 0; mt < 8; ++mt) {
                f32x4_t vv = oacc[mt][nt];
                vv[0] *= iv; vv[1] *= iv; vv[2] *= iv; vv[3] *= iv;
                *(f32x4_t*)&op[mt * 16 + quad * 4] = vv;
            }
        }
    };

    loadQ(qt0);
    resetAcc();
    BAR();

    for (int i = 0; i < J; ++i) {
        const int t  = (i >= n0);
        const int qt = t ? qt1 : qt0;
        const int j  = t ? i - n0 : i;
        if (i == n0) {               // tile switch: flush tile0, start tile1
            storeTile(qt0);
            resetAcc();
            loadQ(qt1);
        }
        const unsigned short* k_s  =
            (const unsigned short*)(smem + ((i & 1) ? OFF_K1 : OFF_K0));
        const unsigned short* vt_s =
            (const unsigned short*)(smem + ((i & 1) ? OFF_VT1 : OFF_VT0));

        // ---- S^T = K Q^T : 4 m-tiles (k) x 2 n-tiles (q) ----
        f32x4_t sa[4][2];
        #pragma unroll
        for (int mt = 0; mt < 4; ++mt)
            #pragma unroll
            for (int nt = 0; nt < 2; ++nt) sa[mt][nt] = (f32x4_t)(0.0f);
        #pragma unroll
        for (int kc = 0; kc < 4; ++kc)
            #pragma unroll
            for (int mt = 0; mt < 4; ++mt) {
                bf16x8_t kf = *(const bf16x8_t*)
                    &k_s[(mt * 16 + l16) * LDK + kc * 32 + quad * 8];
                sa[mt][0] = __builtin_amdgcn_mfma_f32_16x16x32_bf16(kf, qf[0][kc], sa[mt][0], 0, 0, 0);
                sa[mt][1] = __builtin_amdgcn_mfma_f32_16x16x32_bf16(kf, qf[1][kc], sa[mt][1], 0, 0, 0);
            }

        // ---- causal mask on the diagonal k-tile ----
        if (j == qt) {
            #pragma unroll
            for (int nt = 0; nt < 2; ++nt) {
                const int ql = wave * 32 + nt * 16 + l16;
                #pragma unroll
                for (int mt = 0; mt < 4; ++mt)
                    #pragma unroll
                    for (int r = 0; r < 4; ++r)
                        if (mt * 16 + quad * 4 + r > ql) sa[mt][nt][r] = -INFINITY;
            }
        }

        // ---- online softmax (exp2), in-lane 16 + 2 shfls per nt ----
        float a[2];
        bf16x4_t pkv[2][4];
        #pragma unroll
        for (int nt = 0; nt < 2; ++nt) {
            f32x4_t mv = vmax4(vmax4(sa[0][nt], sa[1][nt]),
                               vmax4(sa[2][nt], sa[3][nt]));
            float mx = fmaxf(fmaxf(mv[0], mv[1]), fmaxf(mv[2], mv[3]));
            mx = fmaxf(mx, __shfl_xor(mx, 16));
            mx = fmaxf(mx, __shfl_xor(mx, 32));
            float mnew = fmaxf(mi[nt], mx);
            a[nt] = exp2f(mi[nt] - mnew);
            mi[nt] = mnew;
            #pragma unroll
            for (int mt = 0; mt < 4; ++mt) {
                #pragma unroll
                for (int r = 0; r < 4; ++r) sa[mt][nt][r] = exp2f(sa[mt][nt][r] - mnew);
                pkv[nt][mt][0] = (__bf16)sa[mt][nt][0];
                pkv[nt][mt][1] = (__bf16)sa[mt][nt][1];
                pkv[nt][mt][2] = (__bf16)sa[mt][nt][2];
                pkv[nt][mt][3] = (__bf16)sa[mt][nt][3];
            }
            f32x4_t sv = (sa[0][nt] + sa[1][nt]) + (sa[2][nt] + sa[3][nt]);
            float rs = (sv[0] + sv[1]) + (sv[2] + sv[3]);
            rs += __shfl_xor(rs, 16);
            rs += __shfl_xor(rs, 32);
            li[nt] = li[nt] * a[nt] + rs;
        }

        // ---- P^T -> LDS (wave-local rows; same-wave ds ordering) ----
        #pragma unroll
        for (int nt = 0; nt < 2; ++nt)
            #pragma unroll
            for (int mt = 0; mt < 4; ++mt)
                *(bf16x4_t*)&pT_s[(wave * 32 + nt * 16 + l16) * LDPT + mt * 16 + quad * 4] =
                    pkv[nt][mt];

        // ---- rescale O^T ----
        #pragma unroll
        for (int mt = 0; mt < 8; ++mt)
            #pragma unroll
            for (int nt = 0; nt < 2; ++nt) {
                oacc[mt][nt][0] *= a[nt]; oacc[mt][nt][1] *= a[nt];
                oacc[mt][nt][2] *= a[nt]; oacc[mt][nt][3] *= a[nt];
            }

        // ---- O^T += V^T P^T : 8 m-tiles (d) x 2 n-tiles (q) ----
        #pragma unroll
        for (int kc = 0; kc < 2; ++kc) {
            bf16x8_t pb0 = *(const bf16x8_t*)
                &pT_s[(wave * 32 + l16) * LDPT + kc * 32 + quad * 8];
            bf16x8_t pb1 = *(const bf16x8_t*)
                &pT_s[(wave * 32 + 16 + l16) * LDPT + kc * 32 + quad * 8];
            #pragma unroll
            for (int mt = 0; mt < 8; ++mt) {
                bf16x8_t vf = *(const bf16x8_t*)
                    &vt_s[(mt * 16 + l16) * LDV + kc * 32 + quad * 8];
                oacc[mt][0] = __builtin_amdgcn_mfma_f32_16x16x32_bf16(vf, pb0, oacc[mt][0], 0, 0, 0);
                oacc[mt][1] = __builtin_amdgcn_mfma_f32_16x16x32_bf16(vf, pb1, oacc[mt][1], 0, 0, 0);
            }
        }
        BAR();
    }

    storeTile(qt1);
}

extern "C" void kernel_launch(void* const* d_in, const int* in_sizes, int n_in,
                              void* d_out, int out_size, void* d_ws, size_t ws_size,
                              hipStream_t stream) {
    const float* q = (const float*)d_in[0];
    const float* k = (const float*)d_in[1];
    const float* v = (const float*)d_in[2];
    float* out = (float*)d_out;
    fa_fwd<<<dim3((SS / 128) * HH), dim3(256), 0, stream>>>(q, k, v, out);
}